// Round 8
// baseline (101.945 us; speedup 1.0000x reference)
//
#include <hip/hip_runtime.h>

// Problem constants (from reference): B=256, IN=1024, OUT=1024, fp32.
#define BB   256
#define IN_  1024
#define OUTN 1024

// Round-8: occupancy test. r4/r5/r7 all pin at ~42 us = ~24 us VALU issue
// (3 full-rate x 2cyc + exp@8cyc per elem) + ~18 us stall. LDS traffic was
// exonerated (r5 8B/elem == r7 2B/elem == same dur). Hypothesis: the stall
// is un-hidden exp-result latency; fix = more waves/SIMD with an idle LDS
// pipe. Keep r7's 4x4 micro-tile + stride-16 cells + plain partial stores;
// shrink KC 128->64 (NI=16) so LDS = 34 KB -> 4 blocks/CU, 16 waves/CU,
// 4 waves/SIMD (vs r7's 2). Unroll i-loop x2 for cross-iteration ILP.
#define TBb  64
#define TOo  64
#define NI   16
#define KC   (IN_ / NI)   // 64
#define LSTR (KC + 4)     // 68 floats: 16B-aligned rows, 2-way banks (free)

#define LOG2E 1.4426950408889634f

// leaky_clamp(v,0,1,0.1) == med3(v, 0.1*v, 0.9 + 0.1*v)  (3 instructions).
__device__ __forceinline__ float leaky_clamp01(float v) {
    return __builtin_amdgcn_fmed3f(v, 0.1f * v, fmaf(0.1f, v, 0.9f));
}

// Numerics: |tau*z| <= ~0.9 (x~N(0,1), aw in [-0.016,0.16], tau=exp(0)=1) ->
// NO max-subtraction pass. t = x * (tau*log2e*aw) [scale folded into staged
// w]; d = sum exp2(t), n = sum exp2(t)*t; s = n / (d * tau * log2e).
// Chunked partials are plain associative sums.
__global__ __launch_bounds__(256, 4)
void esm_partial_kernel(const float* __restrict__ x,
                        const float* __restrict__ w,
                        const float* __restrict__ log_tau,
                        float* __restrict__ dpart,
                        float* __restrict__ npart) {
    __shared__ float xs[TBb][LSTR];    // 17 KB, x staged raw
    __shared__ float wls[TOo][LSTR];   // 17 KB, w staged clamped*scale

    const int tid = threadIdx.x;
    const int bid = blockIdx.x;
    // ic,ot in low bits: XCD-local blocks share one w i-slice (L2 locality).
    const int ic = bid & 15;             // i-chunk 0..15
    const int ot = (bid >> 4) & 15;      // o tile  0..15
    const int bt = bid >> 8;             // b tile  0..3
    const int b0 = bt * TBb;
    const int o0 = ot * TOo;
    const int i0 = ic * KC;

    const float scale = __expf(log_tau[0]) * LOG2E;   // tau * log2(e)

    // Stage 64 rows x 64 i of x and w: 1024 f4 per array, 4 f4 per thread.
    // 16-lane clusters read 256 B contiguous (coalesced); b128 LDS writes
    // hit consecutive bank quads (0 extra cycles, measured r3-r7).
    const int srow = tid >> 4;           // 0..15 (+16 per t)
    const int si4  = (tid & 15) << 2;    // 0..60
    #pragma unroll
    for (int t = 0; t < 4; ++t) {
        const int row = srow + 16 * t;
        *(float4*)&xs[row][si4] =
            *(const float4*)&x[(size_t)(b0 + row) * IN_ + i0 + si4];
        const float4 v = *(const float4*)&w[(size_t)(o0 + row) * IN_ + i0 + si4];
        float4 wo;
        wo.x = leaky_clamp01(v.x) * scale;
        wo.y = leaky_clamp01(v.y) * scale;
        wo.z = leaky_clamp01(v.z) * scale;
        wo.w = leaky_clamp01(v.w) * scale;
        *(float4*)&wls[row][si4] = wo;
    }
    __syncthreads();   // one barrier per block

    // 16x16 thread grid; cells at STRIDE 16: b = b0+ty+16a, o = o0+tx+16c.
    // w-row reads: 16 distinct addrs, banks tx*4 mod 32 -> 2-way + broadcast
    // (free). x-row reads: 4-addr broadcast (free).
    const int tx = tid & 15;
    const int ty = tid >> 4;

    float dacc[4][4] = {{0.f}};
    float nacc[4][4] = {{0.f}};

    #pragma unroll 2   // let the scheduler hoist iter i+1's 8 ds_reads
    for (int i = 0; i < KC; i += 4) {
        float4 xv[4], wv[4];
        #pragma unroll
        for (int a = 0; a < 4; ++a) xv[a] = *(const float4*)&xs[ty + 16 * a][i];
        #pragma unroll
        for (int c = 0; c < 4; ++c) wv[c] = *(const float4*)&wls[tx + 16 * c][i];
        #pragma unroll
        for (int a = 0; a < 4; ++a) {
            #pragma unroll
            for (int c = 0; c < 4; ++c) {
                const float t0 = xv[a].x * wv[c].x;
                const float t1 = xv[a].y * wv[c].y;
                const float t2 = xv[a].z * wv[c].z;
                const float t3 = xv[a].w * wv[c].w;
                const float e0 = __builtin_amdgcn_exp2f(t0);
                const float e1 = __builtin_amdgcn_exp2f(t1);
                const float e2 = __builtin_amdgcn_exp2f(t2);
                const float e3 = __builtin_amdgcn_exp2f(t3);
                dacc[a][c] += ((e0 + e1) + (e2 + e3));
                nacc[a][c] = fmaf(e0, t0, fmaf(e1, t1,
                             fmaf(e2, t2, fmaf(e3, t3, nacc[a][c]))));
            }
        }
    }

    // Plain coalesced partial stores (consecutive tx -> consecutive o).
    float* __restrict__ dp = dpart + (size_t)ic * BB * OUTN;
    float* __restrict__ np = npart + (size_t)ic * BB * OUTN;
    #pragma unroll
    for (int a = 0; a < 4; ++a) {
        const size_t rb = (size_t)(b0 + ty + 16 * a) * OUTN + o0 + tx;
        #pragma unroll
        for (int c = 0; c < 4; ++c) {
            dp[rb + 16 * c] = dacc[a][c];
            np[rb + 16 * c] = nacc[a][c];
        }
    }
}

__global__ __launch_bounds__(256)
void esm_finalize_kernel(const float* __restrict__ dpart,
                         const float* __restrict__ npart,
                         const float* __restrict__ log_tau,
                         float* __restrict__ out) {
    const int idx = blockIdx.x * 256 + threadIdx.x;   // float4 index
    const float inv = 1.0f / (__expf(log_tau[0]) * LOG2E);
    float4 ds = {0.f, 0.f, 0.f, 0.f}, ns = {0.f, 0.f, 0.f, 0.f};
    #pragma unroll
    for (int icn = 0; icn < NI; ++icn) {
        const float4 d4 = ((const float4*)dpart)[(size_t)icn * (BB * OUTN / 4) + idx];
        const float4 n4 = ((const float4*)npart)[(size_t)icn * (BB * OUTN / 4) + idx];
        ds.x += d4.x; ds.y += d4.y; ds.z += d4.z; ds.w += d4.w;
        ns.x += n4.x; ns.y += n4.y; ns.z += n4.z; ns.w += n4.w;
    }
    float4 o4;
    o4.x = ns.x / ds.x * inv;
    o4.y = ns.y / ds.y * inv;
    o4.z = ns.z / ds.z * inv;
    o4.w = ns.w / ds.w * inv;
    ((float4*)out)[idx] = o4;
}

extern "C" void kernel_launch(void* const* d_in, const int* in_sizes, int n_in,
                              void* d_out, int out_size, void* d_ws, size_t ws_size,
                              hipStream_t stream) {
    const float* x  = (const float*)d_in[0];   // (256, 1024)
    const float* w  = (const float*)d_in[1];   // (1024, 1024)
    const float* lt = (const float*)d_in[2];   // scalar log_tau
    float* out = (float*)d_out;                // (256, 1024)

    float* dpart = (float*)d_ws;                          // 16 MB
    float* npart = dpart + (size_t)NI * BB * OUTN;        // 16 MB

    // Every ws cell is overwritten by plain stores -> no memset needed.
    esm_partial_kernel<<<(BB / TBb) * (OUTN / TOo) * NI, 256, 0, stream>>>(
        x, w, lt, dpart, npart);
    esm_finalize_kernel<<<(BB * OUTN) / 1024, 256, 0, stream>>>(
        dpart, npart, lt, out);
}